// Round 1
// baseline (149.327 us; speedup 1.0000x reference)
//
#include <hip/hip_runtime.h>

#define Bdim 4
#define Cdim 128
#define Hdim 96
#define Wdim 96
#define HW   (Hdim*Wdim)        // 9216
#define NOC  18                 // rot conv output channels
#define PADH 98                 // rows: true row r -> padded row r+1
#define PADW 104                // cols: true col c -> padded col c+3

// ---------------------------------------------------------------------------
// Kernel 1: zero-padded copy of x into workspace.
// xpad[b][c][r][col]: r = true_row+1 (1..96 valid), col = true_col+3 (3..98 valid)
// ---------------------------------------------------------------------------
__global__ __launch_bounds__(256) void pad_kernel(const float* __restrict__ x,
                                                  float* __restrict__ xpad) {
    int idx = blockIdx.x * 256 + threadIdx.x;
    const int total = Bdim * Cdim * PADH * PADW;
    if (idx >= total) return;
    int col  = idx % PADW;
    int rest = idx / PADW;
    int row  = rest % PADH;
    int bc   = rest / PADH;
    int tr = row - 1;
    int tc = col - 3;
    float v = 0.f;
    if ((unsigned)tr < (unsigned)Hdim && (unsigned)tc < (unsigned)Wdim)
        v = x[(size_t)bc * HW + tr * Wdim + tc];
    xpad[idx] = v;
}

// ---------------------------------------------------------------------------
// Kernel 2: rot = conv3x3(x, rot_w) + rot_b   (fp32 direct conv)
// thread = (b, oc, pixel-quad): 4 output pixels along w, loop over c.
// grid (9, 18, 4), block 256. Weights are wave-uniform -> scalar loads.
// ---------------------------------------------------------------------------
__global__ __launch_bounds__(256) void conv_kernel(const float* __restrict__ xpad,
                                                   const float* __restrict__ rot_w,
                                                   const float* __restrict__ rot_b,
                                                   float* __restrict__ rot) {
    int idx = blockIdx.x * 256 + threadIdx.x;   // 0..2303 = 96 h * 24 quads
    int oc  = blockIdx.y;
    int b   = blockIdx.z;
    int h   = idx / 24;
    int wq  = idx % 24;

    float acc0 = 0.f, acc1 = 0.f, acc2 = 0.f, acc3 = 0.f;
    const float* xb = xpad + (size_t)b * Cdim * PADH * PADW;
    const float* wb = rot_w + (size_t)oc * Cdim * 9;

    for (int c = 0; c < Cdim; ++c) {
        const float* xr = xb + (c * PADH + h) * PADW + 4 * wq;
        const float* wc = wb + c * 9;
#pragma unroll
        for (int di = 0; di < 3; ++di) {
            float4 u = *reinterpret_cast<const float4*>(xr + di * PADW);
            float4 v = *reinterpret_cast<const float4*>(xr + di * PADW + 4);
            float w0 = wc[di * 3 + 0];
            float w1 = wc[di * 3 + 1];
            float w2 = wc[di * 3 + 2];
            // local positions p[k+kj+2] over [u.x..u.w, v.x..v.w]
            acc0 = fmaf(u.z, w0, acc0); acc0 = fmaf(u.w, w1, acc0); acc0 = fmaf(v.x, w2, acc0);
            acc1 = fmaf(u.w, w0, acc1); acc1 = fmaf(v.x, w1, acc1); acc1 = fmaf(v.y, w2, acc1);
            acc2 = fmaf(v.x, w0, acc2); acc2 = fmaf(v.y, w1, acc2); acc2 = fmaf(v.z, w2, acc2);
            acc3 = fmaf(v.y, w0, acc3); acc3 = fmaf(v.z, w1, acc3); acc3 = fmaf(v.w, w2, acc3);
        }
    }
    float bias = rot_b[oc];
    float4 o;
    o.x = acc0 + bias; o.y = acc1 + bias; o.z = acc2 + bias; o.w = acc3 + bias;
    *reinterpret_cast<float4*>(rot + ((size_t)(b * NOC + oc) * HW) + h * Wdim + 4 * wq) = o;
}

// ---------------------------------------------------------------------------
// Kernel 3: per-pixel bilinear coefficients.
// For each (b, tap t, pixel): coords -> normalized (aw0, bh0, pair-index).
// Clamp case (h0==3 / w0==3, frac==0) folded so bottom/right coeff is 1-coef.
// coef[(b*9+t)*HW + hw] = float4(aw0, bh0, as_float(r*3+w0), 0)
// ---------------------------------------------------------------------------
__global__ __launch_bounds__(256) void coef_kernel(const float* __restrict__ rot,
                                                   float4* __restrict__ coef) {
    int idx = blockIdx.x * 256 + threadIdx.x;   // 0..36863
    int b  = idx / HW;
    int hw = idx % HW;
    const float* rb = rot + (size_t)b * NOC * HW + hw;
#pragma unroll
    for (int t = 0; t < 9; ++t) {
        int i = t / 3, j = t % 3;
        float ch = rb[(2 * t + 0) * HW] + (0.5f + (float)i);
        float cw = rb[(2 * t + 1) * HW] + (0.5f + (float)j);
        ch = fminf(fmaxf(ch, 0.f), 3.f);
        cw = fminf(fmaxf(cw, 0.f), 3.f);
        float h0f = floorf(ch), w0f = floorf(cw);
        float lh = ch - h0f, lw = cw - w0f;
        int h0 = (int)h0f, w0 = (int)w0f;
        float bh0 = 1.f - lh;
        float aw0 = 1.f - lw;
        if (h0 >= 3) { h0 = 2; bh0 = 0.f; }   // all weight on row 3 (lh==0 there)
        if (w0 >= 3) { w0 = 2; aw0 = 0.f; }   // all weight on col 3 (lw==0 there)
        float4 cf;
        cf.x = aw0;
        cf.y = bh0;
        cf.z = __int_as_float(h0 * 3 + w0);   // pair index 0..8
        cf.w = 0.f;
        coef[(size_t)(b * 9 + t) * HW + hw] = cf;
    }
}

// ---------------------------------------------------------------------------
// Kernel 4: apply. out[b,c,h,w] = sum_t wsamp(t) * xpad[b,c,h+di,w+dj]
// block (64 hw, 4 c); weight pairs staged in LDS: wp[c][r(0..3)][w0(0..2)] float2.
// Per tap: one dwordx4 coef load, two ds_read_b64 (second at +24B), one x load.
// ---------------------------------------------------------------------------
__global__ __launch_bounds__(256) void apply_kernel(const float* __restrict__ xpad,
                                                    const float4* __restrict__ coef,
                                                    const float* __restrict__ weight,
                                                    float* __restrict__ out) {
    __shared__ float2 wp[4 * 12];
    int tx = threadIdx.x;            // 0..63 -> hw
    int ty = threadIdx.y;            // 0..3  -> c within tile
    int tid = ty * 64 + tx;
    int cbase = blockIdx.y * 4;
    if (tid < 48) {
        int cc = tid / 12;
        int e  = tid % 12;
        int r  = e / 3, w0 = e % 3;
        const float* wrow = weight + (size_t)(cbase + cc) * 16 + r * 4 + w0;
        wp[tid] = make_float2(wrow[0], wrow[1]);
    }
    __syncthreads();

    int hw = blockIdx.x * 64 + tx;
    int b  = blockIdx.z;
    int c  = cbase + ty;
    int h  = hw / Wdim;
    int w  = hw % Wdim;
    const float*  xb  = xpad + ((size_t)(b * Cdim + c) * PADH + h) * PADW + w + 2;
    const float2* wpc = wp + ty * 12;

    float acc = 0.f;
#pragma unroll
    for (int t = 0; t < 9; ++t) {
        float4 cf = coef[(size_t)(b * 9 + t) * HW + hw];
        int   idx = __float_as_int(cf.z);
        float2 g0 = wpc[idx];        // top row pair
        float2 g1 = wpc[idx + 3];    // bottom row pair (+1 row = +3 entries)
        float aw0 = cf.x, bh0 = cf.y;
        float aw1 = 1.f - aw0, bh1 = 1.f - bh0;
        float r0 = fmaf(g0.y, aw1, g0.x * aw0);
        float r1 = fmaf(g1.y, aw1, g1.x * aw0);
        float ws = fmaf(bh1, r1, bh0 * r0);
        int di = t / 3, dj = t % 3;
        float xv = xb[di * PADW + dj];
        acc = fmaf(ws, xv, acc);
    }
    out[(size_t)(b * Cdim + c) * HW + hw] = acc;
}

// ---------------------------------------------------------------------------
extern "C" void kernel_launch(void* const* d_in, const int* in_sizes, int n_in,
                              void* d_out, int out_size, void* d_ws, size_t ws_size,
                              hipStream_t stream) {
    const float* x      = (const float*)d_in[0];
    const float* rot_w  = (const float*)d_in[1];
    const float* rot_b  = (const float*)d_in[2];
    const float* weight = (const float*)d_in[3];
    float* out = (float*)d_out;

    char* ws = (char*)d_ws;
    const size_t xpad_n = (size_t)Bdim * Cdim * PADH * PADW;       // 5,218,304 floats
    const size_t rot_n  = (size_t)Bdim * NOC * HW;                  // 663,552 floats
    float*  xpad = (float*)ws;
    size_t off = ((xpad_n * 4 + 255) / 256) * 256;
    float*  rot  = (float*)(ws + off);
    off += ((rot_n * 4 + 255) / 256) * 256;
    float4* coef = (float4*)(ws + off);                             // 331,776 float4

    const int pad_total = Bdim * Cdim * PADH * PADW;
    pad_kernel<<<(pad_total + 255) / 256, 256, 0, stream>>>(x, xpad);
    conv_kernel<<<dim3(9, NOC, Bdim), 256, 0, stream>>>(xpad, rot_w, rot_b, rot);
    coef_kernel<<<(Bdim * HW) / 256, 256, 0, stream>>>(rot, coef);
    apply_kernel<<<dim3(HW / 64, Cdim / 4, Bdim), dim3(64, 4), 0, stream>>>(xpad, coef, weight, out);
}

// Round 2
// 122.219 us; speedup vs baseline: 1.2218x; 1.2218x over previous
//
#include <hip/hip_runtime.h>

#define Bdim 4
#define Cdim 128
#define Hdim 96
#define Wdim 96
#define HW   (Hdim*Wdim)        // 9216
#define NOC  18                 // rot conv output channels
#define PADH 98                 // rows: true row r -> padded row r+1
#define PADW 104                // cols: true col c -> padded col c+3
#define CCHUNK 32               // channels per conv chunk
#define NCHUNK 4                // number of conv chunks

// ---------------------------------------------------------------------------
// Kernel 1: zero-padded copy of x into workspace.
// xpad[b][c][r][col]: r = true_row+1 (1..96 valid), col = true_col+3 (3..98 valid)
// ---------------------------------------------------------------------------
__global__ __launch_bounds__(256) void pad_kernel(const float* __restrict__ x,
                                                  float* __restrict__ xpad) {
    int idx = blockIdx.x * 256 + threadIdx.x;
    const int total = Bdim * Cdim * PADH * PADW;
    if (idx >= total) return;
    int col  = idx % PADW;
    int rest = idx / PADW;
    int row  = rest % PADH;
    int bc   = rest / PADH;
    int tr = row - 1;
    int tc = col - 3;
    float v = 0.f;
    if ((unsigned)tr < (unsigned)Hdim && (unsigned)tc < (unsigned)Wdim)
        v = x[(size_t)bc * HW + tr * Wdim + tc];
    xpad[idx] = v;
}

// ---------------------------------------------------------------------------
// Kernel 2: rot partial conv. Block = 16x16 pixel tile, ALL 18 oc, 32-c chunk.
// x tile staged in LDS once per block; 18 independent acc chains per thread.
// rot_part[chunk][b][oc][HW] partial sums (reduced in coef_kernel).
// ---------------------------------------------------------------------------
__global__ __launch_bounds__(256) void conv_kernel(const float* __restrict__ xpad,
                                                   const float* __restrict__ rot_w,
                                                   float* __restrict__ rot_part) {
    __shared__ float xs[CCHUNK][18][19];
    int tid = threadIdx.x;
    int tx = tid & 15, ty = tid >> 4;
    int tile  = blockIdx.x;          // 0..35 (6x6 tiles of 16x16)
    int b     = blockIdx.y;
    int chunk = blockIdx.z;
    int th = (tile / 6) * 16;
    int tw = (tile % 6) * 16;
    int c0 = chunk * CCHUNK;

    // stage 32c x 18x18 halo tile (padded coords: rows th.., cols tw+2..)
    const float* xb = xpad + ((size_t)(b * Cdim + c0) * PADH + th) * PADW + tw + 2;
    for (int i = tid; i < CCHUNK * 18 * 18; i += 256) {
        int c   = i / 324;
        int rem = i - c * 324;
        int r   = rem / 18;
        int cc  = rem - r * 18;
        xs[c][r][cc] = xb[(c * PADH + r) * PADW + cc];
    }
    __syncthreads();

    float acc[NOC];
#pragma unroll
    for (int o = 0; o < NOC; ++o) acc[o] = 0.f;

    const float* wbase = rot_w + (size_t)c0 * 9;   // + oc*1152 + cl*9
    for (int cl = 0; cl < CCHUNK; ++cl) {
        float xv[9];
#pragma unroll
        for (int di = 0; di < 3; ++di)
#pragma unroll
            for (int dj = 0; dj < 3; ++dj)
                xv[di * 3 + dj] = xs[cl][ty + di][tx + dj];
        const float* wc = wbase + cl * 9;
#pragma unroll
        for (int o = 0; o < NOC; ++o) {
            const float* w = wc + o * (Cdim * 9);
            float a = acc[o];
            a = fmaf(xv[0], w[0], a);
            a = fmaf(xv[1], w[1], a);
            a = fmaf(xv[2], w[2], a);
            a = fmaf(xv[3], w[3], a);
            a = fmaf(xv[4], w[4], a);
            a = fmaf(xv[5], w[5], a);
            a = fmaf(xv[6], w[6], a);
            a = fmaf(xv[7], w[7], a);
            a = fmaf(xv[8], w[8], a);
            acc[o] = a;
        }
    }

    int h = th + ty, w_ = tw + tx;
    float* dst = rot_part + ((size_t)(chunk * Bdim + b) * NOC) * HW + h * Wdim + w_;
#pragma unroll
    for (int o = 0; o < NOC; ++o) dst[(size_t)o * HW] = acc[o];
}

// ---------------------------------------------------------------------------
// Kernel 3: reduce conv partials (+bias), then per-pixel bilinear coefficients.
// coef[(b*9+t)*HW + hw] = float4(aw0, bh0, as_float(h0*3+w0), 0)
// ---------------------------------------------------------------------------
__global__ __launch_bounds__(256) void coef_kernel(const float* __restrict__ rot_part,
                                                   const float* __restrict__ rot_b,
                                                   float4* __restrict__ coef) {
    int idx = blockIdx.x * 256 + threadIdx.x;   // 0..36863
    int b  = idx / HW;
    int hw = idx % HW;
    const size_t CS = (size_t)Bdim * NOC * HW;  // chunk stride
    const float* rp = rot_part + (size_t)b * NOC * HW + hw;
#pragma unroll
    for (int t = 0; t < 9; ++t) {
        int i = t / 3, j = t % 3;
        float ch = rot_b[2 * t + 0] + (0.5f + (float)i);
        float cw = rot_b[2 * t + 1] + (0.5f + (float)j);
#pragma unroll
        for (int k = 0; k < NCHUNK; ++k) {
            ch += rp[k * CS + (2 * t + 0) * HW];
            cw += rp[k * CS + (2 * t + 1) * HW];
        }
        ch = fminf(fmaxf(ch, 0.f), 3.f);
        cw = fminf(fmaxf(cw, 0.f), 3.f);
        float h0f = floorf(ch), w0f = floorf(cw);
        float lh = ch - h0f, lw = cw - w0f;
        int h0 = (int)h0f, w0 = (int)w0f;
        float bh0 = 1.f - lh;
        float aw0 = 1.f - lw;
        if (h0 >= 3) { h0 = 2; bh0 = 0.f; }
        if (w0 >= 3) { w0 = 2; aw0 = 0.f; }
        float4 cf;
        cf.x = aw0;
        cf.y = bh0;
        cf.z = __int_as_float(h0 * 3 + w0);
        cf.w = 0.f;
        coef[(size_t)(b * 9 + t) * HW + hw] = cf;
    }
}

// ---------------------------------------------------------------------------
// Kernel 4: apply. out[b,c,h,w] = sum_t wsamp(t) * xpad[b,c,h+di,w+dj]
// ---------------------------------------------------------------------------
__global__ __launch_bounds__(256) void apply_kernel(const float* __restrict__ xpad,
                                                    const float4* __restrict__ coef,
                                                    const float* __restrict__ weight,
                                                    float* __restrict__ out) {
    __shared__ float2 wp[4 * 12];
    int tx = threadIdx.x;            // 0..63 -> hw
    int ty = threadIdx.y;            // 0..3  -> c within tile
    int tid = ty * 64 + tx;
    int cbase = blockIdx.y * 4;
    if (tid < 48) {
        int cc = tid / 12;
        int e  = tid % 12;
        int r  = e / 3, w0 = e % 3;
        const float* wrow = weight + (size_t)(cbase + cc) * 16 + r * 4 + w0;
        wp[tid] = make_float2(wrow[0], wrow[1]);
    }
    __syncthreads();

    int hw = blockIdx.x * 64 + tx;
    int b  = blockIdx.z;
    int c  = cbase + ty;
    int h  = hw / Wdim;
    int w  = hw % Wdim;
    const float*  xb  = xpad + ((size_t)(b * Cdim + c) * PADH + h) * PADW + w + 2;
    const float2* wpc = wp + ty * 12;

    float acc = 0.f;
#pragma unroll
    for (int t = 0; t < 9; ++t) {
        float4 cf = coef[(size_t)(b * 9 + t) * HW + hw];
        int   idx = __float_as_int(cf.z);
        float2 g0 = wpc[idx];        // top row pair
        float2 g1 = wpc[idx + 3];    // bottom row pair
        float aw0 = cf.x, bh0 = cf.y;
        float aw1 = 1.f - aw0, bh1 = 1.f - bh0;
        float r0 = fmaf(g0.y, aw1, g0.x * aw0);
        float r1 = fmaf(g1.y, aw1, g1.x * aw0);
        float ws = fmaf(bh1, r1, bh0 * r0);
        int di = t / 3, dj = t % 3;
        float xv = xb[di * PADW + dj];
        acc = fmaf(ws, xv, acc);
    }
    out[(size_t)(b * Cdim + c) * HW + hw] = acc;
}

// ---------------------------------------------------------------------------
extern "C" void kernel_launch(void* const* d_in, const int* in_sizes, int n_in,
                              void* d_out, int out_size, void* d_ws, size_t ws_size,
                              hipStream_t stream) {
    const float* x      = (const float*)d_in[0];
    const float* rot_w  = (const float*)d_in[1];
    const float* rot_b  = (const float*)d_in[2];
    const float* weight = (const float*)d_in[3];
    float* out = (float*)d_out;

    char* ws = (char*)d_ws;
    const size_t xpad_n = (size_t)Bdim * Cdim * PADH * PADW;        // 5,218,304 floats
    const size_t rotp_n = (size_t)NCHUNK * Bdim * NOC * HW;         // 2,654,208 floats
    float*  xpad = (float*)ws;
    size_t off = ((xpad_n * 4 + 255) / 256) * 256;
    float*  rot_part = (float*)(ws + off);
    off += ((rotp_n * 4 + 255) / 256) * 256;
    float4* coef = (float4*)(ws + off);                              // 331,776 float4

    const int pad_total = Bdim * Cdim * PADH * PADW;
    pad_kernel<<<(pad_total + 255) / 256, 256, 0, stream>>>(x, xpad);
    conv_kernel<<<dim3(36, Bdim, NCHUNK), 256, 0, stream>>>(xpad, rot_w, rot_part);
    coef_kernel<<<(Bdim * HW) / 256, 256, 0, stream>>>(rot_part, rot_b, coef);
    apply_kernel<<<dim3(HW / 64, Cdim / 4, Bdim), dim3(64, 4), 0, stream>>>(xpad, coef, weight, out);
}

// Round 3
// 83.668 us; speedup vs baseline: 1.7848x; 1.4608x over previous
//
#include <hip/hip_runtime.h>

#define Bdim 4
#define Cdim 128
#define Hdim 96
#define Wdim 96
#define HW   (Hdim*Wdim)        // 9216
#define NOC  18                 // rot conv output channels
#define PADH 98                 // rows: true row r -> padded row r+1
#define PADW 98                 // cols: true col c -> padded col c+1

// ---------------------------------------------------------------------------
// Kernel 1: zero-padded copy of x into workspace. offset (+1,+1).
// ---------------------------------------------------------------------------
__global__ __launch_bounds__(256) void pad_kernel(const float* __restrict__ x,
                                                  float* __restrict__ xpad) {
    int idx = blockIdx.x * 256 + threadIdx.x;
    const int total = Bdim * Cdim * PADH * PADW;
    if (idx >= total) return;
    int col  = idx % PADW;
    int rest = idx / PADW;
    int row  = rest % PADH;
    int bc   = rest / PADH;
    int tr = row - 1;
    int tc = col - 1;
    float v = 0.f;
    if ((unsigned)tr < (unsigned)Hdim && (unsigned)tc < (unsigned)Wdim)
        v = x[(size_t)bc * HW + tr * Wdim + tc];
    xpad[idx] = v;
}

// ---------------------------------------------------------------------------
// Kernel 2: rot partial conv.
// Block = 16x32 pixel tile (16 cols x 32 rows), ALL 18 oc, CC-channel chunk.
// Thread = 2 vertically adjacent pixels. Weights in LDS (broadcast b128 reads),
// x read direct from global (L1). 36 independent FMA chains per thread.
// rot_part[chunk][b][oc][HW].
// ---------------------------------------------------------------------------
template<int CC>
__global__ __launch_bounds__(256) void conv_kernel(const float* __restrict__ xpad,
                                                   const float* __restrict__ rot_w,
                                                   float* __restrict__ rot_part) {
    __shared__ float wlds[CC][NOC][12];
    int tid = threadIdx.x;
    int chunk = blockIdx.z;
    int b     = blockIdx.y;
    int c0    = chunk * CC;

    // stage weights: rot_w[o][c0+cl][k], k<9
    for (int i = tid; i < CC * NOC * 9; i += 256) {
        int cl  = i / (NOC * 9);
        int rem = i - cl * (NOC * 9);
        int o   = rem / 9;
        int k   = rem - o * 9;
        wlds[cl][o][k] = rot_w[(size_t)o * (Cdim * 9) + (c0 + cl) * 9 + k];
    }
    __syncthreads();

    int tilex = blockIdx.x % 6;        // 6 tiles of 16 cols
    int tiley = blockIdx.x / 6;        // 3 tiles of 32 rows
    int tx  = tid & 15;
    int tyq = tid >> 4;                // 0..15
    int h0 = tiley * 32 + 2 * tyq;     // two output rows h0, h0+1
    int w_ = tilex * 16 + tx;

    const float* xb = xpad + ((size_t)(b * Cdim + c0) * PADH + h0) * PADW + w_;

    float acc[NOC][2];
#pragma unroll
    for (int o = 0; o < NOC; ++o) { acc[o][0] = 0.f; acc[o][1] = 0.f; }

    float xv[4][3];
#pragma unroll
    for (int r = 0; r < 4; ++r)
#pragma unroll
        for (int j = 0; j < 3; ++j)
            xv[r][j] = xb[r * PADW + j];

    for (int cl = 0; cl < CC; ++cl) {
        float xn[4][3];
        if (cl + 1 < CC) {
            const float* xr = xb + (size_t)(cl + 1) * PADH * PADW;
#pragma unroll
            for (int r = 0; r < 4; ++r)
#pragma unroll
                for (int j = 0; j < 3; ++j)
                    xn[r][j] = xr[r * PADW + j];
        }
#pragma unroll
        for (int o = 0; o < NOC; ++o) {
            const float* wp = &wlds[cl][o][0];
            float4 wa = *reinterpret_cast<const float4*>(wp);
            float4 wb4 = *reinterpret_cast<const float4*>(wp + 4);
            float  w8 = wp[8];
            float a0 = acc[o][0], a1 = acc[o][1];
            a0 = fmaf(xv[0][0], wa.x, a0); a1 = fmaf(xv[1][0], wa.x, a1);
            a0 = fmaf(xv[0][1], wa.y, a0); a1 = fmaf(xv[1][1], wa.y, a1);
            a0 = fmaf(xv[0][2], wa.z, a0); a1 = fmaf(xv[1][2], wa.z, a1);
            a0 = fmaf(xv[1][0], wa.w, a0); a1 = fmaf(xv[2][0], wa.w, a1);
            a0 = fmaf(xv[1][1], wb4.x, a0); a1 = fmaf(xv[2][1], wb4.x, a1);
            a0 = fmaf(xv[1][2], wb4.y, a0); a1 = fmaf(xv[2][2], wb4.y, a1);
            a0 = fmaf(xv[2][0], wb4.z, a0); a1 = fmaf(xv[3][0], wb4.z, a1);
            a0 = fmaf(xv[2][1], wb4.w, a0); a1 = fmaf(xv[3][1], wb4.w, a1);
            a0 = fmaf(xv[2][2], w8,  a0); a1 = fmaf(xv[3][2], w8,  a1);
            acc[o][0] = a0; acc[o][1] = a1;
        }
#pragma unroll
        for (int r = 0; r < 4; ++r)
#pragma unroll
            for (int j = 0; j < 3; ++j)
                xv[r][j] = xn[r][j];
    }

    float* dst = rot_part + ((size_t)(chunk * Bdim + b) * NOC) * HW + h0 * Wdim + w_;
#pragma unroll
    for (int o = 0; o < NOC; ++o) {
        dst[(size_t)o * HW]        = acc[o][0];
        dst[(size_t)o * HW + Wdim] = acc[o][1];
    }
}

// ---------------------------------------------------------------------------
// Kernel 3: reduce conv partials (+bias) -> bilinear coefficient quads.
// coefq[(b*9+t)*HW+hw] = (q00, q01, q10, float(h0*3+w0)); q11 = 1-q00-q01-q10.
// grid.y splits the 9 taps into 3 groups of 3.
// ---------------------------------------------------------------------------
template<int NCH>
__global__ __launch_bounds__(256) void coef_kernel(const float* __restrict__ rot_part,
                                                   const float* __restrict__ rot_b,
                                                   float4* __restrict__ coefq) {
    int idx = blockIdx.x * 256 + threadIdx.x;   // 0..36863
    int b  = idx / HW;
    int hw = idx % HW;
    int t0 = blockIdx.y * 3;
#pragma unroll
    for (int tt = 0; tt < 3; ++tt) {
        int t = t0 + tt;
        int i = t / 3, j = t % 3;
        float ch = rot_b[2 * t + 0] + (0.5f + (float)i);
        float cw = rot_b[2 * t + 1] + (0.5f + (float)j);
#pragma unroll
        for (int k = 0; k < NCH; ++k) {
            const float* rp = rot_part + ((size_t)(k * Bdim + b) * NOC) * HW + hw;
            ch += rp[(size_t)(2 * t + 0) * HW];
            cw += rp[(size_t)(2 * t + 1) * HW];
        }
        ch = fminf(fmaxf(ch, 0.f), 3.f);
        cw = fminf(fmaxf(cw, 0.f), 3.f);
        float h0f = floorf(ch), w0f = floorf(cw);
        float lh = ch - h0f, lw = cw - w0f;
        int h0 = (int)h0f, w0 = (int)w0f;
        float bh0 = 1.f - lh;
        float aw0 = 1.f - lw;
        if (h0 >= 3) { h0 = 2; bh0 = 0.f; }
        if (w0 >= 3) { w0 = 2; aw0 = 0.f; }
        float4 cf;
        cf.x = aw0 * bh0;                 // q00 -> W[h0][w0]
        cf.y = (1.f - aw0) * bh0;         // q01 -> W[h0][w0+1]
        cf.z = aw0 * (1.f - bh0);         // q10 -> W[h0+1][w0]
        cf.w = (float)(h0 * 3 + w0);      // table index
        coefq[(size_t)(b * 9 + t) * HW + hw] = cf;
    }
}

// ---------------------------------------------------------------------------
// Kernel 4: apply. Thread = 1 pixel, loops 32 channels (ty picks c-range).
// Per-c packed bilinear quad table wq[c][9] (float4) in LDS, one b128 per tap.
// ---------------------------------------------------------------------------
__global__ __launch_bounds__(256) void apply_kernel(const float* __restrict__ xpad,
                                                    const float4* __restrict__ coefq,
                                                    const float* __restrict__ weight,
                                                    float* __restrict__ out) {
    __shared__ float4 wq[Cdim * 9];
    int tid = threadIdx.y * 64 + threadIdx.x;
    for (int i = tid; i < Cdim * 9; i += 256) {
        int c = i / 9, t = i - c * 9;
        int r = t / 3, s = t - r * 3;
        const float* wb = weight + (size_t)c * 16 + r * 4 + s;
        wq[i] = make_float4(wb[0], wb[1], wb[4], wb[5]);
    }
    __syncthreads();

    int px = blockIdx.x * 64 + threadIdx.x;   // 0..36863 (64 | HW)
    int b  = px / HW;
    int hw = px % HW;
    int h  = hw / Wdim;
    int wc = hw % Wdim;

    float q00[9], q01[9], q10[9], q11[9];
    int lidx[9];
#pragma unroll
    for (int t = 0; t < 9; ++t) {
        float4 cf = coefq[(size_t)(b * 9 + t) * HW + hw];
        q00[t] = cf.x;
        q01[t] = cf.y;
        q10[t] = cf.z;
        q11[t] = 1.f - cf.x - cf.y - cf.z;
        lidx[t] = (int)cf.w;
    }

    int c0 = threadIdx.y * 32;
    const float* xb = xpad + ((size_t)(b * Cdim + c0) * PADH + h) * PADW + wc;
    float* ob = out + ((size_t)(b * Cdim + c0)) * HW + hw;

#pragma unroll 2
    for (int k = 0; k < 32; ++k) {
        int c = c0 + k;
        float acc = 0.f;
#pragma unroll
        for (int t = 0; t < 9; ++t) {
            float4 g = wq[c * 9 + lidx[t]];
            float ws = q00[t] * g.x;
            ws = fmaf(q01[t], g.y, ws);
            ws = fmaf(q10[t], g.z, ws);
            ws = fmaf(q11[t], g.w, ws);
            acc = fmaf(ws, xb[(t / 3) * PADW + (t % 3)], acc);
        }
        ob[(size_t)k * HW] = acc;
        xb += (size_t)PADH * PADW;
    }
}

// ---------------------------------------------------------------------------
extern "C" void kernel_launch(void* const* d_in, const int* in_sizes, int n_in,
                              void* d_out, int out_size, void* d_ws, size_t ws_size,
                              hipStream_t stream) {
    const float* x      = (const float*)d_in[0];
    const float* rot_w  = (const float*)d_in[1];
    const float* rot_b  = (const float*)d_in[2];
    const float* weight = (const float*)d_in[3];
    float* out = (float*)d_out;

    char* ws = (char*)d_ws;
    const size_t xpad_n  = (size_t)Bdim * Cdim * PADH * PADW;   // 4,917,248 floats
    const size_t coefq_n = (size_t)Bdim * 9 * HW;               // 331,776 float4

    auto align256 = [](size_t v) { return ((v + 255) / 256) * 256; };
    size_t off_xpad = 0;
    size_t off_rot  = align256(xpad_n * 4);

    // choose chunking by available workspace
    const size_t rotp8 = (size_t)8 * Bdim * NOC * HW * 4;
    const size_t need8 = off_rot + align256(rotp8) + coefq_n * 16;

    float*  xpad = (float*)(ws + off_xpad);
    float*  rot_part = (float*)(ws + off_rot);

    const int pad_total = Bdim * Cdim * PADH * PADW;
    pad_kernel<<<(pad_total + 255) / 256, 256, 0, stream>>>(x, xpad);

    if (ws_size >= need8) {
        float4* coefq = (float4*)(ws + off_rot + align256(rotp8));
        conv_kernel<16><<<dim3(18, Bdim, 8), 256, 0, stream>>>(xpad, rot_w, rot_part);
        coef_kernel<8><<<dim3(Bdim * HW / 256, 3), 256, 0, stream>>>(rot_part, rot_b, coefq);
        apply_kernel<<<dim3(Bdim * HW / 64), dim3(64, 4), 0, stream>>>(xpad, coefq, weight, out);
    } else {
        const size_t rotp4 = (size_t)4 * Bdim * NOC * HW * 4;
        float4* coefq = (float4*)(ws + off_rot + align256(rotp4));
        conv_kernel<32><<<dim3(18, Bdim, 4), 256, 0, stream>>>(xpad, rot_w, rot_part);
        coef_kernel<4><<<dim3(Bdim * HW / 256, 3), 256, 0, stream>>>(rot_part, rot_b, coefq);
        apply_kernel<<<dim3(Bdim * HW / 64), dim3(64, 4), 0, stream>>>(xpad, coefq, weight, out);
    }
}